// Round 1
// baseline (1161.469 us; speedup 1.0000x reference)
//
#include <hip/hip_runtime.h>
#include <math.h>

#define PRIME_Y 2654435761u

struct LevelParams { float scale; unsigned res; unsigned size; unsigned offset; };
struct EncParams { LevelParams lv[16]; };

struct alignas(8) F2 { float x, y; };

__global__ __launch_bounds__(256) void plane_fwd(
    const F2* __restrict__ xy,
    const F2* __restrict__ table,
    const float* __restrict__ w0g,
    const float* __restrict__ w1g,
    const int* __restrict__ boundp,
    float* __restrict__ out,
    EncParams P)
{
  __shared__ float sw0[64 * 32];   // w0[j][i], row-major
  __shared__ float sw1t[64 * 8];   // w1t[j][k] = w1[k][j]
  const int t = threadIdx.x;
  {
    const float4* src = (const float4*)w0g;
    float4* dst = (float4*)sw0;
    #pragma unroll
    for (int it = 0; it < 2; ++it) dst[t + it * 256] = src[t + it * 256];
    #pragma unroll
    for (int it = 0; it < 2; ++it) {
      int s = t + it * 256;
      int j = s >> 3, k = s & 7;
      sw1t[s] = w1g[k * 64 + j];
    }
  }
  __syncthreads();

  const int i = blockIdx.x * 256 + t;
  F2 pxy = xy[i];

  int braw = boundp[0];
  float bf = (braw > 0x00800000) ? __int_as_float(braw) : (float)braw;
  float inv2b = 0.5f / bf;
  float xn = (pxy.x + bf) * inv2b;
  float yn = (pxy.y + bf) * inv2b;

  float cx  = fminf(fmaxf(xn * 2048.0f - 0.5f, 0.0f), 2047.0f);
  float cyv = fminf(fmaxf(yn * 2048.0f - 0.5f, 0.0f), 2047.0f);
  float cx0 = floorf(cx), cy0 = floorf(cyv);
  float u = cx - cx0, v = cyv - cy0;
  float cx1 = fminf(cx0 + 1.0f, 2047.0f);
  float cy1 = fminf(cy0 + 1.0f, 2047.0f);

  const float K = 1.0f / 2048.0f;
  float gx0 = (cx0 + 0.5f) * K;
  float gx1 = (cx1 + 0.5f) * K;

  float out_acc[8];
  #pragma unroll
  for (int k = 0; k < 8; ++k) out_acc[k] = 0.0f;

  #pragma unroll
  for (int pass = 0; pass < 2; ++pass) {
    const float cyp = (pass == 0) ? cy0 : cy1;
    const float gy  = (cyp + 0.5f) * K;
    const float wvp = (pass == 0) ? (1.0f - v) : v;

    float f0[32], f1[32];

    #pragma unroll
    for (int l = 0; l < 16; ++l) {
      const float scale  = P.lv[l].scale;
      const unsigned res  = P.lv[l].res;
      const unsigned size = P.lv[l].size;
      const unsigned off  = P.lv[l].offset;
      const bool hashed = (res * res) > size;  // wave-uniform branch

      // y side (shared by both corners of this pass)
      float py  = fmaf(gy, scale, 0.5f);
      float pgy = floorf(py);
      float fry = py - pgy;
      unsigned uy = (unsigned)pgy;
      float wy0 = 1.0f - fry, wy1 = fry;

      // x side, corner A (cx0) and corner B (cx1)
      float pxa = fmaf(gx0, scale, 0.5f);
      float pga = floorf(pxa);
      float fra = pxa - pga;
      unsigned uxa = (unsigned)pga;
      float wxa0 = 1.0f - fra, wxa1 = fra;

      float pxb = fmaf(gx1, scale, 0.5f);
      float pgb = floorf(pxb);
      float frb = pxb - pgb;
      unsigned uxb = (unsigned)pgb;
      float wxb0 = 1.0f - frb, wxb1 = frb;

      unsigned iA00, iA01, iA10, iA11, iB00, iB01, iB10, iB11;
      if (hashed) {
        const unsigned m = size - 1u;       // hashed levels: size == 2^19
        unsigned hy0 = uy * PRIME_Y;
        unsigned hy1 = (uy + 1u) * PRIME_Y;
        iA00 = (uxa ^ hy0) & m;        iA01 = (uxa ^ hy1) & m;
        iA10 = ((uxa + 1u) ^ hy0) & m; iA11 = ((uxa + 1u) ^ hy1) & m;
        iB00 = (uxb ^ hy0) & m;        iB01 = (uxb ^ hy1) & m;
        iB10 = ((uxb + 1u) ^ hy0) & m; iB11 = ((uxb + 1u) ^ hy1) & m;
      } else {
        unsigned b0 = uy * res, b1 = b0 + res;
        unsigned vA00 = uxa + b0,      vA01 = uxa + b1;
        unsigned vA10 = uxa + 1u + b0, vA11 = uxa + 1u + b1;
        unsigned vB00 = uxb + b0,      vB01 = uxb + b1;
        unsigned vB10 = uxb + 1u + b0, vB11 = uxb + 1u + b1;
        // v < 2*size always (v <= res^2 + res <= size + res), so one cond-sub == mod
        iA00 = vA00 >= size ? vA00 - size : vA00;
        iA01 = vA01 >= size ? vA01 - size : vA01;
        iA10 = vA10 >= size ? vA10 - size : vA10;
        iA11 = vA11 >= size ? vA11 - size : vA11;
        iB00 = vB00 >= size ? vB00 - size : vB00;
        iB01 = vB01 >= size ? vB01 - size : vB01;
        iB10 = vB10 >= size ? vB10 - size : vB10;
        iB11 = vB11 >= size ? vB11 - size : vB11;
      }

      F2 tA00 = table[off + iA00];
      F2 tA01 = table[off + iA01];
      F2 tA10 = table[off + iA10];
      F2 tA11 = table[off + iA11];
      F2 tB00 = table[off + iB00];
      F2 tB01 = table[off + iB01];
      F2 tB10 = table[off + iB10];
      F2 tB11 = table[off + iB11];

      float wA00 = wxa0 * wy0, wA01 = wxa0 * wy1, wA10 = wxa1 * wy0, wA11 = wxa1 * wy1;
      float wB00 = wxb0 * wy0, wB01 = wxb0 * wy1, wB10 = wxb1 * wy0, wB11 = wxb1 * wy1;

      f0[2 * l]     = wA00 * tA00.x + wA01 * tA01.x + wA10 * tA10.x + wA11 * tA11.x;
      f0[2 * l + 1] = wA00 * tA00.y + wA01 * tA01.y + wA10 * tA10.y + wA11 * tA11.y;
      f1[2 * l]     = wB00 * tB00.x + wB01 * tB01.x + wB10 * tB10.x + wB11 * tB11.x;
      f1[2 * l + 1] = wB00 * tB00.y + wB01 * tB01.y + wB10 * tB10.y + wB11 * tB11.y;
    }

    // MLP for both corners of this pass; fold bilinear blend into layer 2.
    const float wA = (1.0f - u) * wvp;
    const float wB = u * wvp;

    #pragma unroll 4
    for (int j = 0; j < 64; ++j) {
      const float4* wr = (const float4*)(sw0 + j * 32);
      float h0 = 0.0f, h1 = 0.0f;
      #pragma unroll
      for (int q = 0; q < 8; ++q) {
        float4 w = wr[q];
        h0 = fmaf(f0[4 * q + 0], w.x, h0);
        h0 = fmaf(f0[4 * q + 1], w.y, h0);
        h0 = fmaf(f0[4 * q + 2], w.z, h0);
        h0 = fmaf(f0[4 * q + 3], w.w, h0);
        h1 = fmaf(f1[4 * q + 0], w.x, h1);
        h1 = fmaf(f1[4 * q + 1], w.y, h1);
        h1 = fmaf(f1[4 * q + 2], w.z, h1);
        h1 = fmaf(f1[4 * q + 3], w.w, h1);
      }
      float s = wA * fmaxf(h0, 0.0f) + wB * fmaxf(h1, 0.0f);
      const float4* w1r = (const float4*)(sw1t + j * 8);
      float4 wa = w1r[0], wb = w1r[1];
      out_acc[0] = fmaf(s, wa.x, out_acc[0]);
      out_acc[1] = fmaf(s, wa.y, out_acc[1]);
      out_acc[2] = fmaf(s, wa.z, out_acc[2]);
      out_acc[3] = fmaf(s, wa.w, out_acc[3]);
      out_acc[4] = fmaf(s, wb.x, out_acc[4]);
      out_acc[5] = fmaf(s, wb.y, out_acc[5]);
      out_acc[6] = fmaf(s, wb.z, out_acc[6]);
      out_acc[7] = fmaf(s, wb.w, out_acc[7]);
    }
  }

  float4 o0, o1;
  o0.x = out_acc[0]; o0.y = out_acc[1]; o0.z = out_acc[2]; o0.w = out_acc[3];
  o1.x = out_acc[4]; o1.y = out_acc[5]; o1.z = out_acc[6]; o1.w = out_acc[7];
  float4* op = (float4*)(out + (size_t)i * 8);
  op[0] = o0;
  op[1] = o1;
}

extern "C" void kernel_launch(void* const* d_in, const int* in_sizes, int n_in,
                              void* d_out, int out_size, void* d_ws, size_t ws_size,
                              hipStream_t stream) {
  // Replicate gridencoder's per-level config with the same double-precision
  // math sequence numpy uses (exp2/log2/pow/ceil from libm).
  EncParams P;
  double b = exp2(log2(2048.0 / 16.0) / 15.0);
  unsigned off = 0;
  for (int l = 0; l < 16; ++l) {
    double s = 16.0 * pow(b, (double)l) - 1.0;
    int r = (int)ceil(s) + 1;
    unsigned p = (unsigned)(r * r);
    if (p > 524288u) p = 524288u;        // min(HASHMAP_MAX, r*r)
    p = (p + 7u) / 8u * 8u;              // align to 8 entries
    P.lv[l].scale = (float)s;
    P.lv[l].res = (unsigned)r;
    P.lv[l].size = p;
    P.lv[l].offset = off;
    off += p;
  }

  const int N = in_sizes[0] / 2;  // xy is [N,2]
  plane_fwd<<<N / 256, 256, 0, stream>>>(
      (const F2*)d_in[0], (const F2*)d_in[1],
      (const float*)d_in[2], (const float*)d_in[3],
      (const int*)d_in[4], (float*)d_out, P);
}

// Round 2
// 962.301 us; speedup vs baseline: 1.2070x; 1.2070x over previous
//
#include <hip/hip_runtime.h>
#include <math.h>

#define PRIME_Y 2654435761u

struct LevelParams { float scale; unsigned res; unsigned size; unsigned offset; };
struct EncParams { LevelParams lv[16]; };

struct alignas(8) F2 { float x, y; };

// 4 threads per point: one per bilinear plane corner. Quad-reduce the blended
// output via __shfl_xor. __launch_bounds__(256,4) caps VGPRs at 128 -> 4
// waves/SIMD for latency hiding of the scattered hash-table gathers.
__global__ __launch_bounds__(256, 4) void plane_fwd(
    const F2* __restrict__ xy,
    const F2* __restrict__ table,
    const float* __restrict__ w0g,
    const float* __restrict__ w1g,
    const int* __restrict__ boundp,
    float* __restrict__ out,
    EncParams P)
{
  __shared__ float sw0[64 * 32];   // w0[j][i], row-major
  __shared__ float sw1t[64 * 8];   // w1t[j][k] = w1[k][j]
  const int t = threadIdx.x;
  {
    const float4* src = (const float4*)w0g;
    float4* dst = (float4*)sw0;
    #pragma unroll
    for (int it = 0; it < 2; ++it) dst[t + it * 256] = src[t + it * 256];
    #pragma unroll
    for (int it = 0; it < 2; ++it) {
      int s = t + it * 256;
      int j = s >> 3, k = s & 7;
      sw1t[s] = w1g[k * 64 + j];
    }
  }
  __syncthreads();

  const int gid = blockIdx.x * 256 + t;
  const int p = gid >> 2;        // point index
  const int c = t & 3;           // corner: bit0 = x side, bit1 = y side
  F2 pxy = xy[p];

  int braw = boundp[0];
  float bf = (braw > 0x00800000) ? __int_as_float(braw) : (float)braw;
  float inv2b = 0.5f / bf;
  float xn = (pxy.x + bf) * inv2b;
  float yn = (pxy.y + bf) * inv2b;

  float cx  = fminf(fmaxf(xn * 2048.0f - 0.5f, 0.0f), 2047.0f);
  float cyv = fminf(fmaxf(yn * 2048.0f - 0.5f, 0.0f), 2047.0f);
  float cx0 = floorf(cx), cy0 = floorf(cyv);
  float u = cx - cx0, v = cyv - cy0;
  float cx1 = fminf(cx0 + 1.0f, 2047.0f);
  float cy1 = fminf(cy0 + 1.0f, 2047.0f);

  const float cxc = (c & 1) ? cx1 : cx0;
  const float cyc = (c & 2) ? cy1 : cy0;
  const float wc = ((c & 1) ? u : 1.0f - u) * ((c & 2) ? v : 1.0f - v);

  const float K = 1.0f / 2048.0f;
  const float gx = (cxc + 0.5f) * K;
  const float gy = (cyc + 0.5f) * K;

  float f[32];

  #pragma unroll
  for (int l = 0; l < 16; ++l) {
    const float scale   = P.lv[l].scale;
    const unsigned res  = P.lv[l].res;
    const unsigned size = P.lv[l].size;
    const unsigned off  = P.lv[l].offset;
    const bool hashed = (res * res) > size;  // wave-uniform

    float px = fmaf(gx, scale, 0.5f);
    float pgx = floorf(px);
    float frx = px - pgx;
    unsigned ux = (unsigned)pgx;

    float py = fmaf(gy, scale, 0.5f);
    float pgy = floorf(py);
    float fry = py - pgy;
    unsigned uy = (unsigned)pgy;

    unsigned i00, i01, i10, i11;
    if (hashed) {
      const unsigned m = size - 1u;   // hashed levels: size == 2^19
      unsigned hy0 = uy * PRIME_Y;
      unsigned hy1 = (uy + 1u) * PRIME_Y;
      i00 = (ux ^ hy0) & m;
      i01 = (ux ^ hy1) & m;
      i10 = ((ux + 1u) ^ hy0) & m;
      i11 = ((ux + 1u) ^ hy1) & m;
    } else {
      unsigned b0 = uy * res, b1 = b0 + res;
      unsigned v00 = ux + b0,      v01 = ux + b1;
      unsigned v10 = ux + 1u + b0, v11 = ux + 1u + b1;
      // max index = res*res + res < 2*size, one cond-sub == mod
      i00 = v00 >= size ? v00 - size : v00;
      i01 = v01 >= size ? v01 - size : v01;
      i10 = v10 >= size ? v10 - size : v10;
      i11 = v11 >= size ? v11 - size : v11;
    }

    F2 t00 = table[off + i00];
    F2 t01 = table[off + i01];
    F2 t10 = table[off + i10];
    F2 t11 = table[off + i11];

    float wx0 = 1.0f - frx, wx1 = frx;
    float wy0 = 1.0f - fry, wy1 = fry;
    float w00 = wx0 * wy0, w01 = wx0 * wy1, w10 = wx1 * wy0, w11 = wx1 * wy1;

    f[2 * l]     = w00 * t00.x + w01 * t01.x + w10 * t10.x + w11 * t11.x;
    f[2 * l + 1] = w00 * t00.y + w01 * t01.y + w10 * t10.y + w11 * t11.y;
  }

  // MLP for this corner; fold the bilinear weight into layer-2 accumulation.
  float out_acc[8];
  #pragma unroll
  for (int k = 0; k < 8; ++k) out_acc[k] = 0.0f;

  #pragma unroll 4
  for (int j = 0; j < 64; ++j) {
    const float4* wr = (const float4*)(sw0 + j * 32);
    float h = 0.0f;
    #pragma unroll
    for (int q = 0; q < 8; ++q) {
      float4 w = wr[q];
      h = fmaf(f[4 * q + 0], w.x, h);
      h = fmaf(f[4 * q + 1], w.y, h);
      h = fmaf(f[4 * q + 2], w.z, h);
      h = fmaf(f[4 * q + 3], w.w, h);
    }
    float s = wc * fmaxf(h, 0.0f);
    const float4* w1r = (const float4*)(sw1t + j * 8);
    float4 wa = w1r[0], wb = w1r[1];
    out_acc[0] = fmaf(s, wa.x, out_acc[0]);
    out_acc[1] = fmaf(s, wa.y, out_acc[1]);
    out_acc[2] = fmaf(s, wa.z, out_acc[2]);
    out_acc[3] = fmaf(s, wa.w, out_acc[3]);
    out_acc[4] = fmaf(s, wb.x, out_acc[4]);
    out_acc[5] = fmaf(s, wb.y, out_acc[5]);
    out_acc[6] = fmaf(s, wb.z, out_acc[6]);
    out_acc[7] = fmaf(s, wb.w, out_acc[7]);
  }

  // Quad reduction: sum the 4 corners' weighted outputs.
  #pragma unroll
  for (int k = 0; k < 8; ++k) {
    out_acc[k] += __shfl_xor(out_acc[k], 1, 64);
    out_acc[k] += __shfl_xor(out_acc[k], 2, 64);
  }

  // Each lane of the quad stores its 2 output elements: coalesced 32B/quad.
  float2 o;
  o.x = out_acc[2 * c];
  o.y = out_acc[2 * c + 1];
  *(float2*)(out + (size_t)p * 8 + 2 * c) = o;
}

extern "C" void kernel_launch(void* const* d_in, const int* in_sizes, int n_in,
                              void* d_out, int out_size, void* d_ws, size_t ws_size,
                              hipStream_t stream) {
  EncParams P;
  double b = exp2(log2(2048.0 / 16.0) / 15.0);
  unsigned off = 0;
  for (int l = 0; l < 16; ++l) {
    double s = 16.0 * pow(b, (double)l) - 1.0;
    int r = (int)ceil(s) + 1;
    unsigned p = (unsigned)(r * r);
    if (p > 524288u) p = 524288u;        // min(HASHMAP_MAX, r*r)
    p = (p + 7u) / 8u * 8u;              // align to 8 entries
    P.lv[l].scale = (float)s;
    P.lv[l].res = (unsigned)r;
    P.lv[l].size = p;
    P.lv[l].offset = off;
    off += p;
  }

  const int N = in_sizes[0] / 2;  // xy is [N,2]
  const int threads_total = N * 4;
  plane_fwd<<<threads_total / 256, 256, 0, stream>>>(
      (const F2*)d_in[0], (const F2*)d_in[1],
      (const float*)d_in[2], (const float*)d_in[3],
      (const int*)d_in[4], (float*)d_out, P);
}

// Round 3
// 954.308 us; speedup vs baseline: 1.2171x; 1.0084x over previous
//
#include <hip/hip_runtime.h>
#include <math.h>

#define PRIME_Y 2654435761u

struct LevelParams { float scale; unsigned res; unsigned size; unsigned offset; };
struct EncParams { LevelParams lv[16]; };

struct alignas(8) F2 { float x, y; };

// 4 threads per point: one per bilinear plane corner. Quad-reduce the blended
// output via __shfl_xor. NOTE: no dynamic indexing into register arrays --
// out_acc[2*c] in round 2 forced the accumulator into scratch (1.9 GB of
// scratch writes). Static cndmask selection keeps it in VGPRs.
__global__ __launch_bounds__(256, 4) void plane_fwd(
    const F2* __restrict__ xy,
    const F2* __restrict__ table,
    const float* __restrict__ w0g,
    const float* __restrict__ w1g,
    const int* __restrict__ boundp,
    float* __restrict__ out,
    EncParams P)
{
  __shared__ float sw0[64 * 32];   // w0[j][i], row-major
  __shared__ float sw1t[64 * 8];   // w1t[j][k] = w1[k][j]
  const int t = threadIdx.x;
  {
    const float4* src = (const float4*)w0g;
    float4* dst = (float4*)sw0;
    #pragma unroll
    for (int it = 0; it < 2; ++it) dst[t + it * 256] = src[t + it * 256];
    #pragma unroll
    for (int it = 0; it < 2; ++it) {
      int s = t + it * 256;
      int j = s >> 3, k = s & 7;
      sw1t[s] = w1g[k * 64 + j];
    }
  }
  __syncthreads();

  const int gid = blockIdx.x * 256 + t;
  const int p = gid >> 2;        // point index
  const int c = t & 3;           // corner: bit0 = x side, bit1 = y side
  F2 pxy = xy[p];

  int braw = boundp[0];
  float bf = (braw > 0x00800000) ? __int_as_float(braw) : (float)braw;
  float inv2b = 0.5f / bf;
  float xn = (pxy.x + bf) * inv2b;
  float yn = (pxy.y + bf) * inv2b;

  float cx  = fminf(fmaxf(xn * 2048.0f - 0.5f, 0.0f), 2047.0f);
  float cyv = fminf(fmaxf(yn * 2048.0f - 0.5f, 0.0f), 2047.0f);
  float cx0 = floorf(cx), cy0 = floorf(cyv);
  float u = cx - cx0, v = cyv - cy0;
  float cx1 = fminf(cx0 + 1.0f, 2047.0f);
  float cy1 = fminf(cy0 + 1.0f, 2047.0f);

  const float cxc = (c & 1) ? cx1 : cx0;
  const float cyc = (c & 2) ? cy1 : cy0;
  const float wc = ((c & 1) ? u : 1.0f - u) * ((c & 2) ? v : 1.0f - v);

  const float K = 1.0f / 2048.0f;
  const float gx = (cxc + 0.5f) * K;
  const float gy = (cyc + 0.5f) * K;

  float f[32];

  #pragma unroll
  for (int l = 0; l < 16; ++l) {
    const float scale   = P.lv[l].scale;
    const unsigned res  = P.lv[l].res;
    const unsigned size = P.lv[l].size;
    const unsigned off  = P.lv[l].offset;
    const bool hashed = (res * res) > size;  // wave-uniform

    float px = fmaf(gx, scale, 0.5f);
    float pgx = floorf(px);
    float frx = px - pgx;
    unsigned ux = (unsigned)pgx;

    float py = fmaf(gy, scale, 0.5f);
    float pgy = floorf(py);
    float fry = py - pgy;
    unsigned uy = (unsigned)pgy;

    unsigned i00, i01, i10, i11;
    if (hashed) {
      const unsigned m = size - 1u;   // hashed levels: size == 2^19
      unsigned hy0 = uy * PRIME_Y;
      unsigned hy1 = (uy + 1u) * PRIME_Y;
      i00 = (ux ^ hy0) & m;
      i01 = (ux ^ hy1) & m;
      i10 = ((ux + 1u) ^ hy0) & m;
      i11 = ((ux + 1u) ^ hy1) & m;
    } else {
      unsigned b0 = uy * res, b1 = b0 + res;
      unsigned v00 = ux + b0,      v01 = ux + b1;
      unsigned v10 = ux + 1u + b0, v11 = ux + 1u + b1;
      // max index = res*res + res < 2*size, one cond-sub == mod
      i00 = v00 >= size ? v00 - size : v00;
      i01 = v01 >= size ? v01 - size : v01;
      i10 = v10 >= size ? v10 - size : v10;
      i11 = v11 >= size ? v11 - size : v11;
    }

    F2 t00 = table[off + i00];
    F2 t01 = table[off + i01];
    F2 t10 = table[off + i10];
    F2 t11 = table[off + i11];

    float wx0 = 1.0f - frx, wx1 = frx;
    float wy0 = 1.0f - fry, wy1 = fry;
    float w00 = wx0 * wy0, w01 = wx0 * wy1, w10 = wx1 * wy0, w11 = wx1 * wy1;

    f[2 * l]     = w00 * t00.x + w01 * t01.x + w10 * t10.x + w11 * t11.x;
    f[2 * l + 1] = w00 * t00.y + w01 * t01.y + w10 * t10.y + w11 * t11.y;
  }

  // MLP for this corner; fold the bilinear weight into layer-2 accumulation.
  float out_acc[8];
  #pragma unroll
  for (int k = 0; k < 8; ++k) out_acc[k] = 0.0f;

  #pragma unroll 4
  for (int j = 0; j < 64; ++j) {
    const float4* wr = (const float4*)(sw0 + j * 32);
    float h = 0.0f;
    #pragma unroll
    for (int q = 0; q < 8; ++q) {
      float4 w = wr[q];
      h = fmaf(f[4 * q + 0], w.x, h);
      h = fmaf(f[4 * q + 1], w.y, h);
      h = fmaf(f[4 * q + 2], w.z, h);
      h = fmaf(f[4 * q + 3], w.w, h);
    }
    float s = wc * fmaxf(h, 0.0f);
    const float4* w1r = (const float4*)(sw1t + j * 8);
    float4 wa = w1r[0], wb = w1r[1];
    out_acc[0] = fmaf(s, wa.x, out_acc[0]);
    out_acc[1] = fmaf(s, wa.y, out_acc[1]);
    out_acc[2] = fmaf(s, wa.z, out_acc[2]);
    out_acc[3] = fmaf(s, wa.w, out_acc[3]);
    out_acc[4] = fmaf(s, wb.x, out_acc[4]);
    out_acc[5] = fmaf(s, wb.y, out_acc[5]);
    out_acc[6] = fmaf(s, wb.z, out_acc[6]);
    out_acc[7] = fmaf(s, wb.w, out_acc[7]);
  }

  // Quad reduction: sum the 4 corners' weighted outputs.
  #pragma unroll
  for (int k = 0; k < 8; ++k) {
    out_acc[k] += __shfl_xor(out_acc[k], 1, 64);
    out_acc[k] += __shfl_xor(out_acc[k], 2, 64);
  }

  // Each lane of the quad stores its 2 output elements (elements 2c, 2c+1).
  // STATIC selection only -- no dynamic register-array indexing.
  const bool cl = (c & 1) != 0;
  const bool ch = (c & 2) != 0;
  float a0 = cl ? out_acc[2] : out_acc[0];
  float a1 = cl ? out_acc[3] : out_acc[1];
  float b0 = cl ? out_acc[6] : out_acc[4];
  float b1 = cl ? out_acc[7] : out_acc[5];
  float2 o;
  o.x = ch ? b0 : a0;
  o.y = ch ? b1 : a1;
  *(float2*)(out + (size_t)p * 8 + 2 * c) = o;
}

extern "C" void kernel_launch(void* const* d_in, const int* in_sizes, int n_in,
                              void* d_out, int out_size, void* d_ws, size_t ws_size,
                              hipStream_t stream) {
  EncParams P;
  double b = exp2(log2(2048.0 / 16.0) / 15.0);
  unsigned off = 0;
  for (int l = 0; l < 16; ++l) {
    double s = 16.0 * pow(b, (double)l) - 1.0;
    int r = (int)ceil(s) + 1;
    unsigned p = (unsigned)(r * r);
    if (p > 524288u) p = 524288u;        // min(HASHMAP_MAX, r*r)
    p = (p + 7u) / 8u * 8u;              // align to 8 entries
    P.lv[l].scale = (float)s;
    P.lv[l].res = (unsigned)r;
    P.lv[l].size = p;
    P.lv[l].offset = off;
    off += p;
  }

  const int N = in_sizes[0] / 2;  // xy is [N,2]
  const int threads_total = N * 4;
  plane_fwd<<<threads_total / 256, 256, 0, stream>>>(
      (const F2*)d_in[0], (const F2*)d_in[1],
      (const float*)d_in[2], (const float*)d_in[3],
      (const int*)d_in[4], (float*)d_out, P);
}

// Round 4
// 626.415 us; speedup vs baseline: 1.8542x; 1.5234x over previous
//
#include <hip/hip_runtime.h>
#include <math.h>

#define PRIME_Y 2654435761u

struct LevelParams { float scale; unsigned res; unsigned size; unsigned offset; };
struct EncParams { LevelParams lv[16]; };

struct alignas(8) F2 { float x, y; };

// 4 threads per point, one per bilinear plane corner; quad shfl_xor reduce.
// Round-3 lesson: __launch_bounds__(256,4) made the backend chase 8 waves/EU
// (64 VGPR) and wholesale-spill f[32]/out_acc to scratch (1.9 GB of scratch
// writes). Plain __launch_bounds__(256) here: let regalloc keep arrays in
// VGPRs.
// Round-3 lesson #2: MLP weights are wave-uniform -> read straight from
// global with uniform indices so they lower to s_load (scalar cache), not
// 512 ds_read_b128/thread (the LDS pipe was a ~650 us floor by itself).
__global__ __launch_bounds__(256) void plane_fwd(
    const F2* __restrict__ xy,
    const F2* __restrict__ table,
    const float* __restrict__ w0g,
    const float* __restrict__ w1g,
    const int* __restrict__ boundp,
    float* __restrict__ out,
    EncParams P)
{
  const int t = threadIdx.x;
  const int gid = blockIdx.x * 256 + t;
  const int p = gid >> 2;        // point index
  const int c = t & 3;           // corner: bit0 = x side, bit1 = y side
  F2 pxy = xy[p];

  int braw = boundp[0];
  float bf = (braw > 0x00800000) ? __int_as_float(braw) : (float)braw;
  float inv2b = 0.5f / bf;
  float xn = (pxy.x + bf) * inv2b;
  float yn = (pxy.y + bf) * inv2b;

  float cx  = fminf(fmaxf(xn * 2048.0f - 0.5f, 0.0f), 2047.0f);
  float cyv = fminf(fmaxf(yn * 2048.0f - 0.5f, 0.0f), 2047.0f);
  float cx0 = floorf(cx), cy0 = floorf(cyv);
  float u = cx - cx0, v = cyv - cy0;
  float cx1 = fminf(cx0 + 1.0f, 2047.0f);
  float cy1 = fminf(cy0 + 1.0f, 2047.0f);

  const float cxc = (c & 1) ? cx1 : cx0;
  const float cyc = (c & 2) ? cy1 : cy0;
  const float wc = ((c & 1) ? u : 1.0f - u) * ((c & 2) ? v : 1.0f - v);

  const float K = 1.0f / 2048.0f;
  const float gx = (cxc + 0.5f) * K;
  const float gy = (cyc + 0.5f) * K;

  float f[32];

  #pragma unroll
  for (int l = 0; l < 16; ++l) {
    const float scale   = P.lv[l].scale;
    const unsigned res  = P.lv[l].res;
    const unsigned size = P.lv[l].size;
    const unsigned off  = P.lv[l].offset;
    const bool hashed = (res * res) > size;  // wave-uniform

    float px = fmaf(gx, scale, 0.5f);
    float pgx = floorf(px);
    float frx = px - pgx;
    unsigned ux = (unsigned)pgx;

    float py = fmaf(gy, scale, 0.5f);
    float pgy = floorf(py);
    float fry = py - pgy;
    unsigned uy = (unsigned)pgy;

    unsigned i00, i01, i10, i11;
    if (hashed) {
      const unsigned m = size - 1u;   // hashed levels: size == 2^19
      unsigned hy0 = uy * PRIME_Y;
      unsigned hy1 = (uy + 1u) * PRIME_Y;
      i00 = (ux ^ hy0) & m;
      i01 = (ux ^ hy1) & m;
      i10 = ((ux + 1u) ^ hy0) & m;
      i11 = ((ux + 1u) ^ hy1) & m;
    } else {
      unsigned b0 = uy * res, b1 = b0 + res;
      unsigned v00 = ux + b0,      v01 = ux + b1;
      unsigned v10 = ux + 1u + b0, v11 = ux + 1u + b1;
      // max index = res*res + res < 2*size, one cond-sub == mod
      i00 = v00 >= size ? v00 - size : v00;
      i01 = v01 >= size ? v01 - size : v01;
      i10 = v10 >= size ? v10 - size : v10;
      i11 = v11 >= size ? v11 - size : v11;
    }

    F2 t00 = table[off + i00];
    F2 t01 = table[off + i01];
    F2 t10 = table[off + i10];
    F2 t11 = table[off + i11];

    float wx0 = 1.0f - frx, wx1 = frx;
    float wy0 = 1.0f - fry, wy1 = fry;
    float w00 = wx0 * wy0, w01 = wx0 * wy1, w10 = wx1 * wy0, w11 = wx1 * wy1;

    f[2 * l]     = w00 * t00.x + w01 * t01.x + w10 * t10.x + w11 * t11.x;
    f[2 * l + 1] = w00 * t00.y + w01 * t01.y + w10 * t10.y + w11 * t11.y;
  }

  // MLP for this corner; fold the bilinear weight into layer-2 accumulation.
  // All weight addresses depend only on loop counters -> uniform -> s_load.
  float out_acc[8];
  #pragma unroll
  for (int k = 0; k < 8; ++k) out_acc[k] = 0.0f;

  #pragma unroll 2
  for (int j = 0; j < 64; ++j) {
    const float4* wr = (const float4*)(w0g + j * 32);
    float h = 0.0f;
    #pragma unroll
    for (int q = 0; q < 8; ++q) {
      float4 w = wr[q];
      h = fmaf(f[4 * q + 0], w.x, h);
      h = fmaf(f[4 * q + 1], w.y, h);
      h = fmaf(f[4 * q + 2], w.z, h);
      h = fmaf(f[4 * q + 3], w.w, h);
    }
    float s = wc * fmaxf(h, 0.0f);
    #pragma unroll
    for (int k = 0; k < 8; ++k) {
      out_acc[k] = fmaf(s, w1g[k * 64 + j], out_acc[k]);
    }
  }

  // Quad reduction: sum the 4 corners' weighted outputs.
  #pragma unroll
  for (int k = 0; k < 8; ++k) {
    out_acc[k] += __shfl_xor(out_acc[k], 1, 64);
    out_acc[k] += __shfl_xor(out_acc[k], 2, 64);
  }

  // Each lane of the quad stores output elements (2c, 2c+1); static selects.
  const bool cl = (c & 1) != 0;
  const bool ch = (c & 2) != 0;
  float a0 = cl ? out_acc[2] : out_acc[0];
  float a1 = cl ? out_acc[3] : out_acc[1];
  float b0 = cl ? out_acc[6] : out_acc[4];
  float b1 = cl ? out_acc[7] : out_acc[5];
  float2 o;
  o.x = ch ? b0 : a0;
  o.y = ch ? b1 : a1;
  *(float2*)(out + (size_t)p * 8 + 2 * c) = o;
}

extern "C" void kernel_launch(void* const* d_in, const int* in_sizes, int n_in,
                              void* d_out, int out_size, void* d_ws, size_t ws_size,
                              hipStream_t stream) {
  EncParams P;
  double b = exp2(log2(2048.0 / 16.0) / 15.0);
  unsigned off = 0;
  for (int l = 0; l < 16; ++l) {
    double s = 16.0 * pow(b, (double)l) - 1.0;
    int r = (int)ceil(s) + 1;
    unsigned p = (unsigned)(r * r);
    if (p > 524288u) p = 524288u;        // min(HASHMAP_MAX, r*r)
    p = (p + 7u) / 8u * 8u;              // align to 8 entries
    P.lv[l].scale = (float)s;
    P.lv[l].res = (unsigned)r;
    P.lv[l].size = p;
    P.lv[l].offset = off;
    off += p;
  }

  const int N = in_sizes[0] / 2;  // xy is [N,2]
  const int threads_total = N * 4;
  plane_fwd<<<threads_total / 256, 256, 0, stream>>>(
      (const F2*)d_in[0], (const F2*)d_in[1],
      (const float*)d_in[2], (const float*)d_in[3],
      (const int*)d_in[4], (float*)d_out, P);
}